// Round 1
// baseline (375.864 us; speedup 1.0000x reference)
//
#include <hip/hip_runtime.h>

#define N_FEAT 128
#define F4_PER_ROW (N_FEAT / 4)   // 32 float4 per row

// One wave (64 lanes) per output segment. membership is sorted, so each
// segment is a contiguous row range [lo, hi) found by binary search.
// Lane layout: tx = lane&31 selects a float4 column group (32*16B = 512B/row),
//              ty = lane>>5 selects row parity (wave reads 2 rows = 1KB/iter).
__global__ __launch_bounds__(64) void seg_sum_kernel(
    const float* __restrict__ feats,
    const int* __restrict__ membership,
    float* __restrict__ out,
    int n_atoms)
{
    const int seg  = blockIdx.x;
    const int lane = threadIdx.x;

    // Lanes 0 and 1 binary-search for lower_bound(seg) and lower_bound(seg+1).
    int res = 0;
    if (lane < 2) {
        const int target = seg + lane;
        int l = 0, r = n_atoms;
        while (l < r) {
            int m = (l + r) >> 1;
            if (membership[m] < target) l = m + 1; else r = m;
        }
        res = l;
    }
    const int lo = __shfl(res, 0);
    const int hi = __shfl(res, 1);

    const int tx = lane & 31;   // float4 column group
    const int ty = lane >> 5;   // row parity: 0 or 1

    float4 acc = make_float4(0.f, 0.f, 0.f, 0.f);
    const float4* __restrict__ f4 = (const float4*)feats;

    for (int r = lo + ty; r < hi; r += 2) {
        float4 v = f4[r * F4_PER_ROW + tx];
        acc.x += v.x; acc.y += v.y; acc.z += v.z; acc.w += v.w;
    }

    // Fold the odd-parity half-wave into the even half.
    acc.x += __shfl_down(acc.x, 32);
    acc.y += __shfl_down(acc.y, 32);
    acc.z += __shfl_down(acc.z, 32);
    acc.w += __shfl_down(acc.w, 32);

    if (ty == 0) {
        ((float4*)out)[seg * F4_PER_ROW + tx] = acc;
    }
}

extern "C" void kernel_launch(void* const* d_in, const int* in_sizes, int n_in,
                              void* d_out, int out_size, void* d_ws, size_t ws_size,
                              hipStream_t stream) {
    const float* feats      = (const float*)d_in[0];
    const int*   membership = (const int*)d_in[1];
    float*       out        = (float*)d_out;

    const int n_atoms = in_sizes[1];          // 524288 membership entries
    const int batch   = out_size / N_FEAT;    // 16384 segments

    seg_sum_kernel<<<batch, 64, 0, stream>>>(feats, membership, out, n_atoms);
}

// Round 3
// 341.001 us; speedup vs baseline: 1.1022x; 1.1022x over previous
//
#include <hip/hip_runtime.h>

#define N_FEAT 128
#define F4 (N_FEAT / 4)   // 32 float4 per row
#define SEGS_PER_BLOCK 4  // one wave each, 256-thread blocks

// Native clang vector type — accepted by __builtin_nontemporal_load
// (HIP_vector_type float4 is a struct and is rejected).
typedef float vfloat4 __attribute__((ext_vector_type(4)));

// ---------------------------------------------------------------------------
// Kernel A: boundary scatter. membership is sorted; starts[s] = lower_bound(s)
// for s in [0, batch]. Thread i covers s in (membership[i-1], membership[i]];
// thread n-1 also covers the tail (membership[n-1], batch].
// Every starts[] slot is written every call (ws is re-poisoned by harness).
// ---------------------------------------------------------------------------
__global__ __launch_bounds__(256) void seg_starts_kernel(
    const int* __restrict__ membership, int* __restrict__ starts, int n_atoms,
    int batch)
{
    int i = blockIdx.x * blockDim.x + threadIdx.x;
    if (i >= n_atoms) return;
    int cur  = membership[i];
    int prev = (i == 0) ? -1 : membership[i - 1];
    for (int s = prev + 1; s <= cur; ++s) starts[s] = i;
    if (i == n_atoms - 1) {
        for (int s = cur + 1; s <= batch; ++s) starts[s] = n_atoms;
    }
}

// ---------------------------------------------------------------------------
// Kernel B: one wave per segment, 4 waves per block (256 threads -> full
// 32-wave/CU occupancy possible). Lane layout: tx = lane&31 -> float4 column,
// ty = lane>>5 -> row parity. Row loop unrolled x4 -> 4 loads in flight/wave.
// ---------------------------------------------------------------------------
__global__ __launch_bounds__(256) void seg_sum_kernel(
    const float* __restrict__ feats,
    const int* __restrict__ starts,
    float* __restrict__ out,
    int batch)
{
    const int wave = threadIdx.x >> 6;
    const int lane = threadIdx.x & 63;
    const int seg  = blockIdx.x * SEGS_PER_BLOCK + wave;
    if (seg >= batch) return;

    const int lo = starts[seg];
    const int hi = starts[seg + 1];

    const int tx = lane & 31;   // float4 column
    const int ty = lane >> 5;   // row parity: 0 or 1

    const vfloat4* __restrict__ f4 = (const vfloat4*)feats;

    vfloat4 a0 = {0.f, 0.f, 0.f, 0.f};
    vfloat4 a1 = a0, a2 = a0, a3 = a0;

    int r = lo + ty;
    // Main chunks: 4 rows per lane (rows r, r+2, r+4, r+6), 8 rows per wave.
    for (; r + 6 < hi; r += 8) {
        const vfloat4* p = f4 + r * F4 + tx;
        vfloat4 v0 = __builtin_nontemporal_load(p);
        vfloat4 v1 = __builtin_nontemporal_load(p + 2 * F4);
        vfloat4 v2 = __builtin_nontemporal_load(p + 4 * F4);
        vfloat4 v3 = __builtin_nontemporal_load(p + 6 * F4);
        a0 += v0;
        a1 += v1;
        a2 += v2;
        a3 += v3;
    }
    // Remainder rows.
    for (; r < hi; r += 2) {
        a0 += __builtin_nontemporal_load(f4 + r * F4 + tx);
    }

    vfloat4 acc = (a0 + a1) + (a2 + a3);

    // Fold odd-parity half-wave into even half.
    acc.x += __shfl_down(acc.x, 32);
    acc.y += __shfl_down(acc.y, 32);
    acc.z += __shfl_down(acc.z, 32);
    acc.w += __shfl_down(acc.w, 32);

    if (ty == 0) {
        ((vfloat4*)out)[seg * F4 + tx] = acc;
    }
}

extern "C" void kernel_launch(void* const* d_in, const int* in_sizes, int n_in,
                              void* d_out, int out_size, void* d_ws, size_t ws_size,
                              hipStream_t stream) {
    const float* feats      = (const float*)d_in[0];
    const int*   membership = (const int*)d_in[1];
    float*       out        = (float*)d_out;
    int*         starts     = (int*)d_ws;   // (batch + 1) ints

    const int n_atoms = in_sizes[1];          // 524288
    const int batch   = out_size / N_FEAT;    // 16384

    seg_starts_kernel<<<(n_atoms + 255) / 256, 256, 0, stream>>>(
        membership, starts, n_atoms, batch);

    seg_sum_kernel<<<(batch + SEGS_PER_BLOCK - 1) / SEGS_PER_BLOCK, 256, 0,
                     stream>>>(feats, starts, out, batch);
}